// Round 7
// baseline (198.124 us; speedup 1.0000x reference)
//
#include <hip/hip_runtime.h>

#define N_WT_     10
#define WT_LEN_   512
#define FIR_TAPS_ 31
#define N_REFL_   15
#define B_        16
#define L_        160000

constexpr int   TPB   = 256;
constexpr int   TPS   = 1024;          // scan block size
constexpr float INCF  = 0.032f;        // f32(512/16000), jax weak-typed scalar
constexpr int   NG0   = L_ / 16;       // 10000 level-0 groups (of 16 samples)
constexpr int   NG1   = NG0 / 16;      // 625 level-1 groups
constexpr int   NG2   = 40;            // ceil(625/16), pad 625->640
constexpr int   NG3   = 3;             // ceil(40/16),  pad 40->48
constexpr int   WTI   = (WT_LEN_ + 1) * N_WT_;  // 513*10 interleaved (+dup row 0)
constexpr int   WTI4  = WTI + 2;       // pad to 5132 floats (float4-divisible)

// ---------------------------------------------------------------------------
// Kernel 1: level-0 group sums, LDS-free for the sums. Each thread owns one
// group of 16: 4x float4 loads (lane-private 64B line => perfectly
// line-coalesced), then the same sequential f32 fold. The empty asm() blocks
// fp-contraction so the INCF*pitch multiply stays separately rounded.
// FIR filter fused into the first 10 blocks of row b==0; wt2 written
// INTERLEAVED: wt2[i*10+w], row 512 duplicating row 0 (20520 B + 2 pad).
// ---------------------------------------------------------------------------
__global__ __launch_bounds__(TPB) void ysum_kernel(
        const float* __restrict__ pitch, float* __restrict__ y,
        const float* __restrict__ wavetables, const float* __restrict__ fir_h,
        float* __restrict__ wt2) {
    __shared__ float s_pad[WT_LEN_ + 2 * N_REFL_];
    __shared__ float s_h[FIR_TAPS_];
    const int b = blockIdx.y, bx = blockIdx.x, t = threadIdx.x;

    const bool do_fir = (b == 0) && (bx < N_WT_);   // uniform per block
    if (do_fir) {
        if (t < FIR_TAPS_) s_h[t] = fir_h[t];
        for (int j = t; j < WT_LEN_ + 2 * N_REFL_; j += TPB) {
            int src = (j + WT_LEN_ - N_REFL_) % WT_LEN_;
            s_pad[j] = wavetables[bx * WT_LEN_ + src];
        }
        __syncthreads();   // block-uniform condition: safe
        for (int i = t; i < WT_LEN_; i += TPB) {   // i = t and t+256
            float acc = 0.0f;
#pragma unroll
            for (int tap = 0; tap < FIR_TAPS_; ++tap)
                acc = fmaf(s_h[tap], s_pad[i + tap], acc);
            wt2[i * N_WT_ + bx] = acc;
            if (i == 0) wt2[WT_LEN_ * N_WT_ + bx] = acc;  // dup row 0 at row 512
        }
        if (bx == 0 && t == 0) { wt2[WTI] = 0.0f; wt2[WTI + 1] = 0.0f; }  // pad
    }

    const int g = bx * 256 + t;
    if (g < NG0) {
        const float4* p4 = (const float4*)(pitch + (size_t)b * L_ + (size_t)g * 16);
        float4 v0 = p4[0], v1 = p4[1], v2 = p4[2], v3 = p4[3];
        float xs[16] = {v0.x, v0.y, v0.z, v0.w, v1.x, v1.y, v1.z, v1.w,
                        v2.x, v2.y, v2.z, v2.w, v3.x, v3.y, v3.z, v3.w};
        float acc = 0.0f;
#pragma unroll
        for (int i = 0; i < 16; ++i) {
            float inc = INCF * xs[i];
            asm("" : "+v"(inc));       // forbid mul+add contraction
            acc += inc;                // sequential f32 fold
        }
        y[b * NG0 + g] = acc;
    }
}

// ---------------------------------------------------------------------------
// Kernel 2: per-row hierarchical scan (base 16, sequential inner folds),
// running folds == bit-identical to per-endpoint from-scratch folds.
// ---------------------------------------------------------------------------
__global__ __launch_bounds__(TPS) void scan_kernel(
        const float* __restrict__ y, float* __restrict__ S1) {
    __shared__ __align__(16) float s_y[NG0];    // 40 KB
    __shared__ __align__(16) float s_S1[NG0];   // 40 KB
    __shared__ float s_z[NG1];
    __shared__ float s_S2[NG1];
    __shared__ float s_w[NG2], s_S3[NG2];
    __shared__ float s_v[NG3], s_S4[NG3];
    const int b = blockIdx.x, t = threadIdx.x;
    const float* yrow = y + (size_t)b * NG0;
    {   // vectorized row load (NG0 even, row byte offset % 8 == 0)
        const float2* src = (const float2*)yrow;
        float2* dst = (float2*)s_y;
        for (int i = t; i < NG0 / 2; i += TPS) dst[i] = src[i];
    }
    __syncthreads();
    for (int j = t; j < NG1; j += TPS) {
        float a = 0.0f;
        for (int i = 0; i < 16; ++i) a += s_y[16 * j + i];
        s_z[j] = a;
    }
    __syncthreads();
    if (t < NG2) {
        float a = 0.0f;
        int hi = min(16 * t + 16, NG1);
        for (int i = 16 * t; i < hi; ++i) a += s_z[i];
        s_w[t] = a;
    }
    __syncthreads();
    if (t < NG3) {
        float a = 0.0f;
        int hi = min(16 * t + 16, NG2);
        for (int i = 16 * t; i < hi; ++i) a += s_w[i];
        s_v[t] = a;
    }
    __syncthreads();
    if (t == 0) {
        float run = 0.0f;
        for (int m = 0; m < NG3; ++m) { run += s_v[m]; s_S4[m] = run; }
    }
    __syncthreads();
    if (t < NG2) {
        float a = 0.0f;
        for (int i = (t >> 4) << 4; i <= t; ++i) a += s_w[i];
        if (t >= 16) a = a + s_S4[(t >> 4) - 1];
        s_S3[t] = a;
    }
    __syncthreads();
    if (t < NG2) {
        float r = 0.0f;
        float carry = (t > 0) ? s_S3[t - 1] : 0.0f;
        int hi = min(16 * t + 16, NG1);
        for (int k = 16 * t; k < hi; ++k) {
            r += s_z[k];
            s_S2[k] = (t > 0) ? r + carry : r;
        }
    }
    __syncthreads();
    for (int j = t; j < NG1; j += TPS) {
        float r = 0.0f;
        float carry = (j > 0) ? s_S2[j - 1] : 0.0f;
        for (int k = 0; k < 16; ++k) {
            r += s_y[16 * j + k];
            s_S1[16 * j + k] = (j > 0) ? r + carry : r;
        }
    }
    __syncthreads();
    float* S1row = S1 + (size_t)b * NG0;
    {   // vectorized row store
        const float2* src = (const float2*)s_S1;
        float2* dst = (float2*)S1row;
        for (int i = t; i < NG0 / 2; i += TPS) dst[i] = src[i];
    }
}

// ---------------------------------------------------------------------------
// Kernel 3: synth — round-6 structure plus ONE change: the wavetable gather
// also moves off the vector-memory path into LDS. Per block we stage BOTH
// the 10 KB attention slab (coalesced float4, as round 6) and the 20.5 KB
// interleaved wavetable (1283 float4s, 5/thread); the divergent per-sample
// gather becomes 10x ds_read_b64 (~4-way bank conflicts: banks =
// (lo*10+2j) mod 32 — cheap per m136) instead of 10x divergent global
// float2 (~500 L1 line-transactions/wave). Scalar loads still issue before
// staging so HBM latency hides under it. LDS 30.8 KB -> 5 blocks/CU
// (20 waves/CU). Values and arithmetic bit-identical to round 6.
// ---------------------------------------------------------------------------
__global__ __launch_bounds__(TPB) void synth_kernel(
        const float* __restrict__ pitch,
        const float* __restrict__ envelope,
        const float* __restrict__ attention,
        const float* __restrict__ wt2,
        const float* __restrict__ S1,
        float* __restrict__ out) {
    __shared__ __align__(16) float s_at[TPB * N_WT_];  // 10240 B
    __shared__ __align__(16) float s_wt[WTI4];         // 20528 B
    const int b = blockIdx.y, cb = blockIdx.x, t = threadIdx.x;
    const int    l = cb * TPB + t;
    const size_t g = (size_t)b * L_ + l;

    // --- issue independent scalar loads up-front ---
    const float pv  = pitch[g];          // own increment source
    const float p0  = pitch[l];          // batch-row-0 quirk (increment[0])
    const float env = envelope[g];
    const int   g0  = l >> 4;
    const float carry = (g0 > 0) ? S1[(size_t)b * NG0 + g0 - 1] : 0.0f;

    // --- coalesced attention stage: 640 float4s, 2.5 per thread ---
    {
        const float4* asrc = (const float4*)(attention
                + ((size_t)b * L_ + (size_t)cb * TPB) * N_WT_);
        float4* adst = (float4*)s_at;
        adst[t]       = asrc[t];
        adst[t + 256] = asrc[t + 256];
        if (t < (TPB * N_WT_) / 4 - 512) adst[t + 512] = asrc[t + 512];
    }
    // --- coalesced wavetable stage: 1283 float4s, ~5 per thread ---
    {
        const float4* wsrc = (const float4*)wt2;
        float4* wdst = (float4*)s_wt;
        for (int i = t; i < WTI4 / 4; i += TPB) wdst[i] = wsrc[i];
    }
    __syncthreads();  // the only barrier

    const int lane  = t & 63;
    const int r16   = lane & 15;
    const int sbase = lane & ~15;

    float x = INCF * pv;  // f32 increment, separately rounded
    // sequential in-group-of-16 fold via shuffles (bit-exact association;
    // +0.0f predicated adds exact: all partials > 0 since pitch >= 100 Hz)
    float acc = 0.0f;
#pragma unroll
    for (int k = 0; k < 16; ++k) {
        float v = __shfl(x, sbase + k, 64);
        acc += (k <= r16) ? v : 0.0f;
    }
    if (g0 > 0) acc = acc + carry;       // carry add

    float idx = acc - INCF * p0;         // minus increment[0] (batch row 0)
    float r = fmodf(idx, 512.0f);        // lax.rem (exact for y=512)
    if (r < 0.0f) r += 512.0f;           // jnp.remainder sign fixup
    if (512.0f - r < 1e-5f) r = 0.0f;    // the reference's snap
    float fl = floorf(r);
    float alpha = r - fl;
    int lo = (int)fl;

    // rows lo, lo+1 = 20 contiguous floats in LDS (row 512 dups row 0)
    const float2* pw = (const float2*)(s_wt + lo * N_WT_);
    float2 q0 = pw[0], q1 = pw[1], q2 = pw[2], q3 = pw[3], q4 = pw[4];
    float2 q5 = pw[5], q6 = pw[6], q7 = pw[7], q8 = pw[8], q9 = pw[9];
    float loV[10] = {q0.x, q0.y, q1.x, q1.y, q2.x, q2.y, q3.x, q3.y, q4.x, q4.y};
    float hiV[10] = {q5.x, q5.y, q6.x, q6.y, q7.x, q7.y, q8.x, q8.y, q9.x, q9.y};

    // per-thread attention from LDS (same values as the old global float2s)
    const float2* pa = (const float2*)(s_at + t * N_WT_);
    float2 a01 = pa[0], a23 = pa[1], a45 = pa[2], a67 = pa[3], a89 = pa[4];
    float a[10] = {a01.x, a01.y, a23.x, a23.y, a45.x, a45.y,
                   a67.x, a67.y, a89.x, a89.y};

    float a0 = 0.0f;
#pragma unroll
    for (int w = 0; w < N_WT_; ++w)
        a0 += a[w] * (loV[w] + alpha * (hiV[w] - loV[w]));
    out[g] = a0 * env;
}

// ---------------------------------------------------------------------------
extern "C" void kernel_launch(void* const* d_in, const int* in_sizes, int n_in,
                              void* d_out, int out_size, void* d_ws, size_t ws_size,
                              hipStream_t stream) {
    const float* pitch      = (const float*)d_in[0];  // (B, L, 1)
    const float* envelope   = (const float*)d_in[1];  // (B, L, 1)
    const float* attention  = (const float*)d_in[2];  // (B, L, 10)
    const float* wavetables = (const float*)d_in[3];  // (10, 512)
    const float* fir_h      = (const float*)d_in[4];  // (31,)
    float*       out        = (float*)d_out;          // (B, L, 1)

    char*  ws  = (char*)d_ws;
    float* wt2 = (float*)(ws);                         // 20528 B (reserve 32 KiB)
    float* y   = (float*)(ws + 32768);                 // 16*10000*4 = 640 KB
    float* S1  = (float*)(ws + 32768 + 655360);        // 640 KB

    ysum_kernel<<<dim3(40, B_), dim3(TPB), 0, stream>>>(
        pitch, y, wavetables, fir_h, wt2);
    scan_kernel<<<dim3(B_), dim3(TPS), 0, stream>>>(y, S1);
    synth_kernel<<<dim3(NG1, B_), dim3(TPB), 0, stream>>>(
        pitch, envelope, attention, wt2, S1, out);
}

// Round 8
// 184.831 us; speedup vs baseline: 1.0719x; 1.0719x over previous
//
#include <hip/hip_runtime.h>

#define N_WT_     10
#define WT_LEN_   512
#define FIR_TAPS_ 31
#define N_REFL_   15
#define B_        16
#define L_        160000

constexpr int   TPB   = 256;
constexpr int   TPS   = 1024;          // scan block size
constexpr float INCF  = 0.032f;        // f32(512/16000), jax weak-typed scalar
constexpr int   NG0   = L_ / 16;       // 10000 level-0 groups (of 16 samples)
constexpr int   NG1   = NG0 / 16;      // 625 level-1 groups
constexpr int   NG2   = 40;            // ceil(625/16), pad 625->640
constexpr int   NG3   = 3;             // ceil(40/16),  pad 40->48

// ---------------------------------------------------------------------------
// Kernel 1: level-0 group sums, LDS-free for the sums. Each thread owns one
// group of 16: 4x float4 loads (lane-private 64B line => perfectly
// line-coalesced), then the same sequential f32 fold. The empty asm() blocks
// fp-contraction so the INCF*pitch multiply stays separately rounded.
// FIR filter fused into the first 10 blocks of row b==0; wt2 written
// INTERLEAVED: wt2[i*10+w], row 512 duplicating row 0 (20520 B).
// ---------------------------------------------------------------------------
__global__ __launch_bounds__(TPB) void ysum_kernel(
        const float* __restrict__ pitch, float* __restrict__ y,
        const float* __restrict__ wavetables, const float* __restrict__ fir_h,
        float* __restrict__ wt2) {
    __shared__ float s_pad[WT_LEN_ + 2 * N_REFL_];
    __shared__ float s_h[FIR_TAPS_];
    const int b = blockIdx.y, bx = blockIdx.x, t = threadIdx.x;

    const bool do_fir = (b == 0) && (bx < N_WT_);   // uniform per block
    if (do_fir) {
        if (t < FIR_TAPS_) s_h[t] = fir_h[t];
        for (int j = t; j < WT_LEN_ + 2 * N_REFL_; j += TPB) {
            int src = (j + WT_LEN_ - N_REFL_) % WT_LEN_;
            s_pad[j] = wavetables[bx * WT_LEN_ + src];
        }
        __syncthreads();   // block-uniform condition: safe
        for (int i = t; i < WT_LEN_; i += TPB) {   // i = t and t+256
            float acc = 0.0f;
#pragma unroll
            for (int tap = 0; tap < FIR_TAPS_; ++tap)
                acc = fmaf(s_h[tap], s_pad[i + tap], acc);
            wt2[i * N_WT_ + bx] = acc;
            if (i == 0) wt2[WT_LEN_ * N_WT_ + bx] = acc;  // dup row 0 at row 512
        }
    }

    const int g = bx * 256 + t;
    if (g < NG0) {
        const float4* p4 = (const float4*)(pitch + (size_t)b * L_ + (size_t)g * 16);
        float4 v0 = p4[0], v1 = p4[1], v2 = p4[2], v3 = p4[3];
        float xs[16] = {v0.x, v0.y, v0.z, v0.w, v1.x, v1.y, v1.z, v1.w,
                        v2.x, v2.y, v2.z, v2.w, v3.x, v3.y, v3.z, v3.w};
        float acc = 0.0f;
#pragma unroll
        for (int i = 0; i < 16; ++i) {
            float inc = INCF * xs[i];
            asm("" : "+v"(inc));       // forbid mul+add contraction
            acc += inc;                // sequential f32 fold
        }
        y[b * NG0 + g] = acc;
    }
}

// ---------------------------------------------------------------------------
// Kernel 2: per-row hierarchical scan (base 16, sequential inner folds),
// running folds == bit-identical to per-endpoint from-scratch folds.
// ---------------------------------------------------------------------------
__global__ __launch_bounds__(TPS) void scan_kernel(
        const float* __restrict__ y, float* __restrict__ S1) {
    __shared__ __align__(16) float s_y[NG0];    // 40 KB
    __shared__ __align__(16) float s_S1[NG0];   // 40 KB
    __shared__ float s_z[NG1];
    __shared__ float s_S2[NG1];
    __shared__ float s_w[NG2], s_S3[NG2];
    __shared__ float s_v[NG3], s_S4[NG3];
    const int b = blockIdx.x, t = threadIdx.x;
    const float* yrow = y + (size_t)b * NG0;
    {   // vectorized row load (NG0 even, row byte offset % 8 == 0)
        const float2* src = (const float2*)yrow;
        float2* dst = (float2*)s_y;
        for (int i = t; i < NG0 / 2; i += TPS) dst[i] = src[i];
    }
    __syncthreads();
    for (int j = t; j < NG1; j += TPS) {
        float a = 0.0f;
        for (int i = 0; i < 16; ++i) a += s_y[16 * j + i];
        s_z[j] = a;
    }
    __syncthreads();
    if (t < NG2) {
        float a = 0.0f;
        int hi = min(16 * t + 16, NG1);
        for (int i = 16 * t; i < hi; ++i) a += s_z[i];
        s_w[t] = a;
    }
    __syncthreads();
    if (t < NG3) {
        float a = 0.0f;
        int hi = min(16 * t + 16, NG2);
        for (int i = 16 * t; i < hi; ++i) a += s_w[i];
        s_v[t] = a;
    }
    __syncthreads();
    if (t == 0) {
        float run = 0.0f;
        for (int m = 0; m < NG3; ++m) { run += s_v[m]; s_S4[m] = run; }
    }
    __syncthreads();
    if (t < NG2) {
        float a = 0.0f;
        for (int i = (t >> 4) << 4; i <= t; ++i) a += s_w[i];
        if (t >= 16) a = a + s_S4[(t >> 4) - 1];
        s_S3[t] = a;
    }
    __syncthreads();
    if (t < NG2) {
        float r = 0.0f;
        float carry = (t > 0) ? s_S3[t - 1] : 0.0f;
        int hi = min(16 * t + 16, NG1);
        for (int k = 16 * t; k < hi; ++k) {
            r += s_z[k];
            s_S2[k] = (t > 0) ? r + carry : r;
        }
    }
    __syncthreads();
    for (int j = t; j < NG1; j += TPS) {
        float r = 0.0f;
        float carry = (j > 0) ? s_S2[j - 1] : 0.0f;
        for (int k = 0; k < 16; ++k) {
            r += s_y[16 * j + k];
            s_S1[16 * j + k] = (j > 0) ? r + carry : r;
        }
    }
    __syncthreads();
    float* S1row = S1 + (size_t)b * NG0;
    {   // vectorized row store
        const float2* src = (const float2*)s_S1;
        float2* dst = (float2*)S1row;
        for (int i = t; i < NG0 / 2; i += TPS) dst[i] = src[i];
    }
}

// ---------------------------------------------------------------------------
// Kernel 3: synth — one sample per thread, grid 625 x 16, direct global
// wavetable gather (L1-resident 20.5 KB table; LDS-staging it was tested and
// regresses: staging traffic + occupancy loss > TA saving). The block's
// 10 KB attention slab IS staged into LDS with perfectly coalesced float4
// loads (40 line-touches/wave vs 200 for the 40B-strided float2 pattern) —
// that stream misses to HBM, so transaction count matters there. Scalar
// loads issue before staging so HBM latency hides under it. Fold via wave
// shuffles (+0.0f predicated adds exact: all partials > 0, pitch >= 100 Hz).
// ---------------------------------------------------------------------------
__global__ __launch_bounds__(TPB) void synth_kernel(
        const float* __restrict__ pitch,
        const float* __restrict__ envelope,
        const float* __restrict__ attention,
        const float* __restrict__ wt2,
        const float* __restrict__ S1,
        float* __restrict__ out) {
    __shared__ __align__(16) float s_at[TPB * N_WT_];  // 10240 B
    const int b = blockIdx.y, cb = blockIdx.x, t = threadIdx.x;
    const int    l = cb * TPB + t;
    const size_t g = (size_t)b * L_ + l;

    // --- issue independent scalar loads up-front ---
    const float pv  = pitch[g];          // own increment source
    const float p0  = pitch[l];          // batch-row-0 quirk (increment[0])
    const float env = envelope[g];
    const int   g0  = l >> 4;
    const float carry = (g0 > 0) ? S1[(size_t)b * NG0 + g0 - 1] : 0.0f;

    // --- coalesced attention stage: 640 float4s, 2.5 per thread ---
    {
        const float4* asrc = (const float4*)(attention
                + ((size_t)b * L_ + (size_t)cb * TPB) * N_WT_);
        float4* adst = (float4*)s_at;
        adst[t]       = asrc[t];
        adst[t + 256] = asrc[t + 256];
        if (t < (TPB * N_WT_) / 4 - 512) adst[t + 512] = asrc[t + 512];
    }
    __syncthreads();  // the only barrier

    const int lane  = t & 63;
    const int r16   = lane & 15;
    const int sbase = lane & ~15;

    float x = INCF * pv;  // f32 increment, separately rounded
    // sequential in-group-of-16 fold via shuffles (bit-exact association;
    // +0.0f predicated adds exact: all partials > 0 since pitch >= 100 Hz)
    float acc = 0.0f;
#pragma unroll
    for (int k = 0; k < 16; ++k) {
        float v = __shfl(x, sbase + k, 64);
        acc += (k <= r16) ? v : 0.0f;
    }
    if (g0 > 0) acc = acc + carry;       // carry add

    float idx = acc - INCF * p0;         // minus increment[0] (batch row 0)
    float r = fmodf(idx, 512.0f);        // lax.rem (exact for y=512)
    if (r < 0.0f) r += 512.0f;           // jnp.remainder sign fixup
    if (512.0f - r < 1e-5f) r = 0.0f;    // the reference's snap
    float fl = floorf(r);
    float alpha = r - fl;
    int lo = (int)fl;

    // rows lo, lo+1 = 20 contiguous floats in L1/L2-resident wt2
    const float2* pw = (const float2*)(wt2 + lo * N_WT_);
    float2 q0 = pw[0], q1 = pw[1], q2 = pw[2], q3 = pw[3], q4 = pw[4];
    float2 q5 = pw[5], q6 = pw[6], q7 = pw[7], q8 = pw[8], q9 = pw[9];
    float loV[10] = {q0.x, q0.y, q1.x, q1.y, q2.x, q2.y, q3.x, q3.y, q4.x, q4.y};
    float hiV[10] = {q5.x, q5.y, q6.x, q6.y, q7.x, q7.y, q8.x, q8.y, q9.x, q9.y};

    // per-thread attention from LDS (same values as the old global float2s)
    const float2* pa = (const float2*)(s_at + t * N_WT_);
    float2 a01 = pa[0], a23 = pa[1], a45 = pa[2], a67 = pa[3], a89 = pa[4];
    float a[10] = {a01.x, a01.y, a23.x, a23.y, a45.x, a45.y,
                   a67.x, a67.y, a89.x, a89.y};

    float a0 = 0.0f;
#pragma unroll
    for (int w = 0; w < N_WT_; ++w)
        a0 += a[w] * (loV[w] + alpha * (hiV[w] - loV[w]));
    out[g] = a0 * env;
}

// ---------------------------------------------------------------------------
extern "C" void kernel_launch(void* const* d_in, const int* in_sizes, int n_in,
                              void* d_out, int out_size, void* d_ws, size_t ws_size,
                              hipStream_t stream) {
    const float* pitch      = (const float*)d_in[0];  // (B, L, 1)
    const float* envelope   = (const float*)d_in[1];  // (B, L, 1)
    const float* attention  = (const float*)d_in[2];  // (B, L, 10)
    const float* wavetables = (const float*)d_in[3];  // (10, 512)
    const float* fir_h      = (const float*)d_in[4];  // (31,)
    float*       out        = (float*)d_out;          // (B, L, 1)

    char*  ws  = (char*)d_ws;
    float* wt2 = (float*)(ws);                         // 20520 B (reserve 32 KiB)
    float* y   = (float*)(ws + 32768);                 // 16*10000*4 = 640 KB
    float* S1  = (float*)(ws + 32768 + 655360);        // 640 KB

    ysum_kernel<<<dim3(40, B_), dim3(TPB), 0, stream>>>(
        pitch, y, wavetables, fir_h, wt2);
    scan_kernel<<<dim3(B_), dim3(TPS), 0, stream>>>(y, S1);
    synth_kernel<<<dim3(NG1, B_), dim3(TPB), 0, stream>>>(
        pitch, envelope, attention, wt2, S1, out);
}